// Round 1
// 5182.098 us; speedup vs baseline: 1.1229x; 1.1229x over previous
//
#include <hip/hip_runtime.h>
#include <cstdint>

#define PP 4
#define TT 4
#define NN 16384
#define DD 256
#define HH 4
#define EE 131072
#define BB 32
#define KK 10
#define OUTD 4
#define NPG 512
#define DTOT 1280   /* (P+1)*D */
#define FIN 12801
#define HID 6400
#define FCCH 128    /* f-rows per fc_partial chunk */

// ---------------- GEMM: C[16384,1024] = A(lda=DTOT) @ B[256,1024] ----------------
__global__ __launch_bounds__(256) void gemm_xp(const float* __restrict__ A,
                                               const float* __restrict__ Bm,
                                               float* __restrict__ C) {
  __shared__ float As[16][132];
  __shared__ float Bs[16][132];
  const int tid = threadIdx.x;
  const int bm = blockIdx.x;   // 0..127
  const int bn = blockIdx.y;   // 0..7
  const int tx = tid & 15, ty = tid >> 4;
  const int m0 = ty * 8, n0 = tx * 8;
  float acc[8][8] = {};
  const int am  = tid >> 1;
  const int akq = (tid & 1) * 8;
  const int arow = bm * 128 + am;
  const int bk  = tid >> 4;        // 0..15
  const int bn4 = (tid & 15) * 8;  // 0..120

  for (int kt = 0; kt < 256; kt += 16) {
    float4 a0 = *(const float4*)(A + (size_t)arow * DTOT + kt + akq);
    float4 a1 = *(const float4*)(A + (size_t)arow * DTOT + kt + akq + 4);
    float4 b0 = *(const float4*)(Bm + (size_t)(kt + bk) * 1024 + bn * 128 + bn4);
    float4 b1 = *(const float4*)(Bm + (size_t)(kt + bk) * 1024 + bn * 128 + bn4 + 4);
    __syncthreads();
    As[akq + 0][am] = a0.x; As[akq + 1][am] = a0.y;
    As[akq + 2][am] = a0.z; As[akq + 3][am] = a0.w;
    As[akq + 4][am] = a1.x; As[akq + 5][am] = a1.y;
    As[akq + 6][am] = a1.z; As[akq + 7][am] = a1.w;
    *(float4*)&Bs[bk][bn4]     = b0;
    *(float4*)&Bs[bk][bn4 + 4] = b1;
    __syncthreads();
#pragma unroll
    for (int k = 0; k < 16; ++k) {
      float4 x0 = *(const float4*)&As[k][m0];
      float4 x1 = *(const float4*)&As[k][m0 + 4];
      float4 y0 = *(const float4*)&Bs[k][n0];
      float4 y1 = *(const float4*)&Bs[k][n0 + 4];
      float av[8] = {x0.x, x0.y, x0.z, x0.w, x1.x, x1.y, x1.z, x1.w};
      float bv[8] = {y0.x, y0.y, y0.z, y0.w, y1.x, y1.y, y1.z, y1.w};
#pragma unroll
      for (int i = 0; i < 8; ++i)
#pragma unroll
        for (int j = 0; j < 8; ++j) acc[i][j] += av[i] * bv[j];
    }
  }
  const int crow0 = bm * 128 + m0;
  const int ccol0 = bn * 128 + n0;
#pragma unroll
  for (int i = 0; i < 8; ++i) {
    float4 c0 = make_float4(acc[i][0], acc[i][1], acc[i][2], acc[i][3]);
    float4 c1 = make_float4(acc[i][4], acc[i][5], acc[i][6], acc[i][7]);
    *(float4*)(C + (size_t)(crow0 + i) * 1024 + ccol0)     = c0;
    *(float4*)(C + (size_t)(crow0 + i) * 1024 + ccol0 + 4) = c1;
  }
}

// ---------------- per-node attention scores ----------------
__global__ __launch_bounds__(256) void attn_scores(const float* __restrict__ xp,
                                                   const float* __restrict__ av_s,
                                                   const float* __restrict__ av_d,
                                                   float* __restrict__ als,
                                                   float* __restrict__ ald) {
  int i = blockIdx.x;
  int h = threadIdx.x >> 6;
  int lane = threadIdx.x & 63;
  const float* row = xp + ((size_t)i * HH + h) * DD;
  const float* sa = av_s + h * DD;
  const float* da = av_d + h * DD;
  float ss = 0.f, sd = 0.f;
  for (int d = lane; d < DD; d += 64) {
    float v = row[d];
    ss += v * sa[d];
    sd += v * da[d];
  }
  for (int off = 32; off > 0; off >>= 1) {
    ss += __shfl_down(ss, off, 64);
    sd += __shfl_down(sd, off, 64);
  }
  if (lane == 0) { als[i * HH + h] = ss; ald[i * HH + h] = sd; }
}

// ---------------- self-loop init of num/den ----------------
__global__ __launch_bounds__(256) void selfloop_init(const float* __restrict__ xp,
                                                     const float* __restrict__ als,
                                                     const float* __restrict__ ald,
                                                     float* __restrict__ num,
                                                     float* __restrict__ den) {
  int i = blockIdx.x, d = threadIdx.x;
#pragma unroll
  for (int h = 0; h < HH; ++h) {
    float l = als[i * HH + h] + ald[i * HH + h];
    l = l > 0.f ? l : 0.2f * l;
    float w = expf(l);
    size_t o = ((size_t)i * HH + h) * DD + d;
    num[o] = w * xp[o];
    if (d == 0) den[i * HH + h] = w;
  }
}

// ---------------- edge accumulation (atomics) ----------------
__global__ __launch_bounds__(256) void edge_kernel(const int* __restrict__ ei,
                                                   const int* __restrict__ ea,
                                                   const float* __restrict__ als,
                                                   const float* __restrict__ ald,
                                                   const float* __restrict__ xp,
                                                   float* __restrict__ num,
                                                   float* __restrict__ den,
                                                   int t) {
  int e = blockIdx.x;
  int src = ei[e], dst = ei[EE + e];
  if (src == dst || ea[e] != t) return;
  int tid = threadIdx.x;
  if (tid < HH) {
    float l = als[src * HH + tid] + ald[dst * HH + tid];
    l = l > 0.f ? l : 0.2f * l;
    atomicAdd(&den[dst * HH + tid], expf(l));
  }
#pragma unroll
  for (int h = 0; h < HH; ++h) {
    float l = als[src * HH + h] + ald[dst * HH + h];
    l = l > 0.f ? l : 0.2f * l;
    float w = expf(l);
    atomicAdd(&num[((size_t)dst * HH + h) * DD + tid],
              w * xp[((size_t)src * HH + h) * DD + tid]);
  }
}

// ---------------- head mean + bias + leaky + accumulate over t ----------------
__global__ __launch_bounds__(256) void head_mean_acc(const float* __restrict__ num,
                                                     const float* __restrict__ den,
                                                     const float* __restrict__ bias,
                                                     float* __restrict__ acc,
                                                     int first) {
  int i = blockIdx.x, d = threadIdx.x;
  float s = 0.f;
#pragma unroll
  for (int h = 0; h < HH; ++h)
    s += num[((size_t)i * HH + h) * DD + d] / den[i * HH + h];
  float val = s * (1.f / HH) + bias[d];
  val = val > 0.f ? val : 0.01f * val;
  if (first) acc[(size_t)i * DD + d] = val;
  else       acc[(size_t)i * DD + d] += val;
}

__global__ void x_update(const float* __restrict__ acc, float* __restrict__ xc, int p) {
  int i = blockIdx.x, d = threadIdx.x;
  xc[(size_t)i * DTOT + (p + 1) * DD + d] = acc[(size_t)i * DD + d] * (1.f / TT);
}

__global__ void x_copy(const float* __restrict__ x, float* __restrict__ xc) {
  int i = blockIdx.x, d = threadIdx.x;
  xc[(size_t)i * DTOT + d] = x[(size_t)i * DD + d];
}

// ---------------- sort pool: per-graph top-K by last channel ----------------
__global__ __launch_bounds__(256) void sort_pool(const float* __restrict__ xc,
                                                 int* __restrict__ topk) {
  __shared__ float vals[NPG];
  __shared__ float rv[256];
  __shared__ int   ri[256];
  int b = blockIdx.x, tid = threadIdx.x;
  for (int i = tid; i < NPG; i += 256)
    vals[i] = xc[(size_t)(b * NPG + i) * DTOT + (DTOT - 1)];
  __syncthreads();
  for (int k = 0; k < KK; ++k) {
    float bv = -3.4e38f; int bi = NPG;
    for (int i = tid; i < NPG; i += 256) {
      float v = vals[i];
      if (v > bv || (v == bv && i < bi)) { bv = v; bi = i; }
    }
    rv[tid] = bv; ri[tid] = bi;
    __syncthreads();
    for (int s = 128; s > 0; s >>= 1) {
      if (tid < s) {
        float v2 = rv[tid + s]; int i2 = ri[tid + s];
        if (v2 > rv[tid] || (v2 == rv[tid] && i2 < ri[tid])) { rv[tid] = v2; ri[tid] = i2; }
      }
      __syncthreads();
    }
    if (tid == 0) { topk[b * KK + k] = b * NPG + ri[0]; vals[ri[0]] = -3.4e38f; }
    __syncthreads();
  }
}

__global__ void gather_pool(const float* __restrict__ xc, const int* __restrict__ topk,
                            const float* __restrict__ ptype, float* __restrict__ pooledT) {
  int bk = blockIdx.x;  // B*K
  int b = bk / KK, k = bk % KK;
  int node = topk[bk];
  for (int j = threadIdx.x; j < DTOT; j += 256)
    pooledT[(size_t)(k * DTOT + j) * BB + b] = xc[(size_t)node * DTOT + j];
  if (k == 0 && threadIdx.x == 0)
    pooledT[(size_t)(FIN - 1) * BB + b] = ptype[b];
}

// ---------------- FC stage 1: partial[y][j][b] = sum_{f in chunk y} inT[f][b]*W[f][j]
// Register tile: 4 j  x 8 b per thread. Block = 64 j-threads x 4 b-groups -> 256 j/block.
// f chunk (<=128 rows) of inT staged in LDS; W read coalesced float4, f-unrolled x2
// for 2 outstanding 1KB/wave loads. Plain float4 stores (no atomics).
__global__ __launch_bounds__(256) void fc_partial(const float* __restrict__ inT,
                                                  const float* __restrict__ W,
                                                  float* __restrict__ partial,
                                                  int Kdim, int Jdim) {
  __shared__ float rows[FCCH * BB];   // 16 KiB
  const int tid = threadIdx.x;
  const int jt  = tid & 63;           // 64 j-threads
  const int bg  = tid >> 6;           // 4 b-groups
  const int j0  = blockIdx.x * 256 + jt * 4;
  const int b0  = bg * 8;
  const int f0  = blockIdx.y * FCCH;
  int nf = Kdim - f0; if (nf > FCCH) nf = FCCH;

  for (int i = tid * 4; i < nf * BB; i += 1024)
    *(float4*)&rows[i] = *(const float4*)(inT + (size_t)f0 * BB + i);
  __syncthreads();

  float acc[4][8];
#pragma unroll
  for (int a = 0; a < 4; ++a)
#pragma unroll
    for (int b = 0; b < 8; ++b) acc[a][b] = 0.f;

  const float* wp = W + (size_t)f0 * Jdim + j0;
  int ff = 0;
  for (; ff + 2 <= nf; ff += 2) {
    float4 w0 = *(const float4*)(wp + (size_t)(ff + 0) * Jdim);
    float4 w1 = *(const float4*)(wp + (size_t)(ff + 1) * Jdim);
    float4 ra0 = *(const float4*)&rows[(ff + 0) * BB + b0];
    float4 ra1 = *(const float4*)&rows[(ff + 0) * BB + b0 + 4];
    float4 rb0 = *(const float4*)&rows[(ff + 1) * BB + b0];
    float4 rb1 = *(const float4*)&rows[(ff + 1) * BB + b0 + 4];
    float wa[4] = {w0.x, w0.y, w0.z, w0.w};
    float wb[4] = {w1.x, w1.y, w1.z, w1.w};
    float r0[8] = {ra0.x, ra0.y, ra0.z, ra0.w, ra1.x, ra1.y, ra1.z, ra1.w};
    float r1[8] = {rb0.x, rb0.y, rb0.z, rb0.w, rb1.x, rb1.y, rb1.z, rb1.w};
#pragma unroll
    for (int a = 0; a < 4; ++a)
#pragma unroll
      for (int b = 0; b < 8; ++b)
        acc[a][b] += wa[a] * r0[b] + wb[a] * r1[b];
  }
  for (; ff < nf; ++ff) {
    float4 w0 = *(const float4*)(wp + (size_t)ff * Jdim);
    float4 ra0 = *(const float4*)&rows[ff * BB + b0];
    float4 ra1 = *(const float4*)&rows[ff * BB + b0 + 4];
    float wa[4] = {w0.x, w0.y, w0.z, w0.w};
    float r0[8] = {ra0.x, ra0.y, ra0.z, ra0.w, ra1.x, ra1.y, ra1.z, ra1.w};
#pragma unroll
    for (int a = 0; a < 4; ++a)
#pragma unroll
      for (int b = 0; b < 8; ++b)
        acc[a][b] += wa[a] * r0[b];
  }

#pragma unroll
  for (int a = 0; a < 4; ++a) {
    float* op = partial + ((size_t)blockIdx.y * Jdim + (j0 + a)) * BB + b0;
    *(float4*)(op)     = make_float4(acc[a][0], acc[a][1], acc[a][2], acc[a][3]);
    *(float4*)(op + 4) = make_float4(acc[a][4], acc[a][5], acc[a][6], acc[a][7]);
  }
}

// ---------------- FC stage 2: reduce partials + bias + leaky ----------------
__global__ __launch_bounds__(256) void fc_reduce(const float* __restrict__ partial,
                                                 const float* __restrict__ bias,
                                                 float* __restrict__ outT,
                                                 int Y, int Jdim) {
  int idx = blockIdx.x * 256 + threadIdx.x;   // j*BB + b
  if (idx >= Jdim * BB) return;
  size_t stride = (size_t)Jdim * BB;
  float s = 0.f;
  for (int y = 0; y < Y; ++y) s += partial[(size_t)y * stride + idx];
  float v = s + bias[idx / BB];
  outT[idx] = v > 0.f ? v : 0.01f * v;
}

__global__ __launch_bounds__(128) void fc3_kernel(const float* __restrict__ h2T,
                                                  const float* __restrict__ w3,
                                                  const float* __restrict__ b3,
                                                  float* __restrict__ out) {
  int tid = threadIdx.x;  // 128 = 32 b * 4 o
  int o = tid & 3, b = tid >> 2;
  float a0 = 0.f, a1 = 0.f, a2 = 0.f, a3 = 0.f;
  for (int f = 0; f < HID; f += 4) {
    a0 += h2T[(size_t)f * BB + b]       * w3[(size_t)f * OUTD + o];
    a1 += h2T[(size_t)(f + 1) * BB + b] * w3[(size_t)(f + 1) * OUTD + o];
    a2 += h2T[(size_t)(f + 2) * BB + b] * w3[(size_t)(f + 2) * OUTD + o];
    a3 += h2T[(size_t)(f + 3) * BB + b] * w3[(size_t)(f + 3) * OUTD + o];
  }
  out[b * OUTD + o] = a0 + a1 + a2 + a3 + b3[o];
}

extern "C" void kernel_launch(void* const* d_in, const int* in_sizes, int n_in,
                              void* d_out, int out_size, void* d_ws, size_t ws_size,
                              hipStream_t stream) {
  const float* x       = (const float*)d_in[0];
  const float* ptype   = (const float*)d_in[1];
  const float* W       = (const float*)d_in[2];
  const float* att_src = (const float*)d_in[3];
  const float* att_dst = (const float*)d_in[4];
  const float* bias_g  = (const float*)d_in[5];
  const float* fc1_w   = (const float*)d_in[6];
  const float* fc1_b   = (const float*)d_in[7];
  const float* fc2_w   = (const float*)d_in[8];
  const float* fc2_b   = (const float*)d_in[9];
  const float* fc3_w   = (const float*)d_in[10];
  const float* fc3_b   = (const float*)d_in[11];
  const int*   ei      = (const int*)d_in[12];
  const int*   ea      = (const int*)d_in[13];
  float* out = (float*)d_out;

  float* ws = (float*)d_ws;
  size_t o = 0;
  float* xc  = ws + o; o += (size_t)NN * DTOT;
  float* xp  = ws + o; o += (size_t)NN * HH * DD;
  float* num = ws + o; o += (size_t)NN * HH * DD;
  float* den = ws + o; o += (size_t)NN * HH;
  float* als = ws + o; o += (size_t)NN * HH;
  float* ald = ws + o; o += (size_t)NN * HH;
  float* acc = ws + o; o += (size_t)NN * DD;
  float* pooledT = ws + o; o += (size_t)FIN * BB;
  float* h1  = ws + o; o += (size_t)HID * BB;
  float* h2  = ws + o; o += (size_t)HID * BB;
  int* topk  = (int*)(ws + o); o += BB * KK;

  x_copy<<<NN, 256, 0, stream>>>(x, xc);

  for (int p = 0; p < PP; ++p) {
    const float* xin = xc + (size_t)p * DD;  // column slice, row stride DTOT
    for (int t = 0; t < TT; ++t) {
      int pt = p * TT + t;
      gemm_xp<<<dim3(128, 8), 256, 0, stream>>>(xin, W + (size_t)pt * DD * HH * DD, xp);
      attn_scores<<<NN, 256, 0, stream>>>(xp, att_src + (size_t)pt * HH * DD,
                                          att_dst + (size_t)pt * HH * DD, als, ald);
      selfloop_init<<<NN, 256, 0, stream>>>(xp, als, ald, num, den);
      edge_kernel<<<EE, 256, 0, stream>>>(ei, ea, als, ald, xp, num, den, t);
      head_mean_acc<<<NN, 256, 0, stream>>>(num, den, bias_g + (size_t)pt * DD, acc,
                                            t == 0 ? 1 : 0);
    }
    x_update<<<NN, 256, 0, stream>>>(acc, xc, p);
  }

  sort_pool<<<BB, 256, 0, stream>>>(xc, topk);
  gather_pool<<<BB * KK, 256, 0, stream>>>(xc, topk, ptype, pooledT);

  // FC stage. Partial buffer reuses xp (+ spills into num) — both dead after the
  // GAT passes. Max need: ceil(FIN/FCCH)=101 chunks * HID * BB = 20.7M floats,
  // xp..num region spans 33.5M floats; pooledT/h1/h2 live far beyond it.
  float* partial = xp;
  {
    int Y1 = (FIN + FCCH - 1) / FCCH;   // 101
    fc_partial<<<dim3(HID / 256, Y1), 256, 0, stream>>>(pooledT, fc1_w, partial, FIN, HID);
    fc_reduce<<<(HID * BB + 255) / 256, 256, 0, stream>>>(partial, fc1_b, h1, Y1, HID);
    int Y2 = (HID + FCCH - 1) / FCCH;   // 50
    fc_partial<<<dim3(HID / 256, Y2), 256, 0, stream>>>(h1, fc2_w, partial, HID, HID);
    fc_reduce<<<(HID * BB + 255) / 256, 256, 0, stream>>>(partial, fc2_b, h2, Y2, HID);
  }

  fc3_kernel<<<1, 128, 0, stream>>>(h2, fc3_w, fc3_b, out);
}

// Round 2
// 3455.331 us; speedup vs baseline: 1.6840x; 1.4997x over previous
//
#include <hip/hip_runtime.h>
#include <cstdint>

#define PP 4
#define TT 4
#define NN 16384
#define DD 256
#define HH 4
#define EE 131072
#define BB 32
#define KK 10
#define OUTD 4
#define NPG 512
#define DTOT 1280   /* (P+1)*D */
#define FIN 12801
#define HID 6400
#define FCCH 128    /* f-rows per fc_partial chunk */

// ---------------- GEMM: C[16384,1024] = A(lda=DTOT) @ B[256,1024] ----------------
__global__ __launch_bounds__(256) void gemm_xp(const float* __restrict__ A,
                                               const float* __restrict__ Bm,
                                               float* __restrict__ C) {
  __shared__ float As[16][132];
  __shared__ float Bs[16][132];
  const int tid = threadIdx.x;
  const int bm = blockIdx.x;   // 0..127
  const int bn = blockIdx.y;   // 0..7
  const int tx = tid & 15, ty = tid >> 4;
  const int m0 = ty * 8, n0 = tx * 8;
  float acc[8][8] = {};
  const int am  = tid >> 1;
  const int akq = (tid & 1) * 8;
  const int arow = bm * 128 + am;
  const int bk  = tid >> 4;        // 0..15
  const int bn4 = (tid & 15) * 8;  // 0..120

  for (int kt = 0; kt < 256; kt += 16) {
    float4 a0 = *(const float4*)(A + (size_t)arow * DTOT + kt + akq);
    float4 a1 = *(const float4*)(A + (size_t)arow * DTOT + kt + akq + 4);
    float4 b0 = *(const float4*)(Bm + (size_t)(kt + bk) * 1024 + bn * 128 + bn4);
    float4 b1 = *(const float4*)(Bm + (size_t)(kt + bk) * 1024 + bn * 128 + bn4 + 4);
    __syncthreads();
    As[akq + 0][am] = a0.x; As[akq + 1][am] = a0.y;
    As[akq + 2][am] = a0.z; As[akq + 3][am] = a0.w;
    As[akq + 4][am] = a1.x; As[akq + 5][am] = a1.y;
    As[akq + 6][am] = a1.z; As[akq + 7][am] = a1.w;
    *(float4*)&Bs[bk][bn4]     = b0;
    *(float4*)&Bs[bk][bn4 + 4] = b1;
    __syncthreads();
#pragma unroll
    for (int k = 0; k < 16; ++k) {
      float4 x0 = *(const float4*)&As[k][m0];
      float4 x1 = *(const float4*)&As[k][m0 + 4];
      float4 y0 = *(const float4*)&Bs[k][n0];
      float4 y1 = *(const float4*)&Bs[k][n0 + 4];
      float av[8] = {x0.x, x0.y, x0.z, x0.w, x1.x, x1.y, x1.z, x1.w};
      float bv[8] = {y0.x, y0.y, y0.z, y0.w, y1.x, y1.y, y1.z, y1.w};
#pragma unroll
      for (int i = 0; i < 8; ++i)
#pragma unroll
        for (int j = 0; j < 8; ++j) acc[i][j] += av[i] * bv[j];
    }
  }
  const int crow0 = bm * 128 + m0;
  const int ccol0 = bn * 128 + n0;
#pragma unroll
  for (int i = 0; i < 8; ++i) {
    float4 c0 = make_float4(acc[i][0], acc[i][1], acc[i][2], acc[i][3]);
    float4 c1 = make_float4(acc[i][4], acc[i][5], acc[i][6], acc[i][7]);
    *(float4*)(C + (size_t)(crow0 + i) * 1024 + ccol0)     = c0;
    *(float4*)(C + (size_t)(crow0 + i) * 1024 + ccol0 + 4) = c1;
  }
}

// ---------------- per-node attention scores ----------------
__global__ __launch_bounds__(256) void attn_scores(const float* __restrict__ xp,
                                                   const float* __restrict__ av_s,
                                                   const float* __restrict__ av_d,
                                                   float* __restrict__ als,
                                                   float* __restrict__ ald) {
  int i = blockIdx.x;
  int h = threadIdx.x >> 6;
  int lane = threadIdx.x & 63;
  const float* row = xp + ((size_t)i * HH + h) * DD;
  const float* sa = av_s + h * DD;
  const float* da = av_d + h * DD;
  float ss = 0.f, sd = 0.f;
  for (int d = lane; d < DD; d += 64) {
    float v = row[d];
    ss += v * sa[d];
    sd += v * da[d];
  }
  for (int off = 32; off > 0; off >>= 1) {
    ss += __shfl_down(ss, off, 64);
    sd += __shfl_down(sd, off, 64);
  }
  if (lane == 0) { als[i * HH + h] = ss; ald[i * HH + h] = sd; }
}

// ---------------- CSR build: bucket edges by (type, dst), excluding self-loops ----
__global__ void zero_i(int* __restrict__ p, int n) {
  int i = blockIdx.x * 256 + threadIdx.x;
  if (i < n) p[i] = 0;
}

__global__ void csr_count(const int* __restrict__ ei, const int* __restrict__ ea,
                          int* __restrict__ deg) {
  int e = blockIdx.x * 256 + threadIdx.x;
  if (e >= EE) return;
  int s = ei[e], d = ei[EE + e];
  if (s == d) return;
  atomicAdd(&deg[ea[e] * NN + d], 1);
}

// one block, 1024 threads; exclusive scan of deg[TT*NN] -> offs, also init cursor
__global__ __launch_bounds__(1024) void csr_scan(const int* __restrict__ deg,
                                                 int* __restrict__ offs,
                                                 int* __restrict__ cursor) {
  __shared__ int part[1024];
  const int tid = threadIdx.x;
  const int base = tid * (TT * NN / 1024);   // 64 entries per thread
  int s = 0;
  for (int i = 0; i < 64; ++i) s += deg[base + i];
  part[tid] = s;
  __syncthreads();
  for (int off = 1; off < 1024; off <<= 1) {
    int v = (tid >= off) ? part[tid - off] : 0;
    __syncthreads();
    part[tid] += v;
    __syncthreads();
  }
  int run = (tid == 0) ? 0 : part[tid - 1];
  for (int i = 0; i < 64; ++i) {
    offs[base + i] = run;
    cursor[base + i] = run;
    run += deg[base + i];
  }
  if (tid == 1023) offs[TT * NN] = run;
}

__global__ void csr_scatter(const int* __restrict__ ei, const int* __restrict__ ea,
                            int* __restrict__ cursor, int* __restrict__ csr_src) {
  int e = blockIdx.x * 256 + threadIdx.x;
  if (e >= EE) return;
  int s = ei[e], d = ei[EE + e];
  if (s == d) return;
  int pos = atomicAdd(&cursor[ea[e] * NN + d], 1);
  csr_src[pos] = s;
}

// ---------------- fused GAT aggregation (self-loop + edges + head mean) ----------
// block = dst node, thread = channel d. No atomics, no num/den round-trip.
// t<TT-1: accumulate into acc; t==TT-1: write xc slice directly (fused x_update).
__global__ __launch_bounds__(256) void gat_aggregate(const int* __restrict__ offs,
                                                     const int* __restrict__ csr_src,
                                                     const float* __restrict__ als,
                                                     const float* __restrict__ ald,
                                                     const float* __restrict__ xp,
                                                     const float* __restrict__ bias,
                                                     float* __restrict__ acc,
                                                     float* __restrict__ xc,
                                                     int t, int p) {
  const int i = blockIdx.x, d = threadIdx.x;
  float ad[HH], den[HH], numv[HH];
#pragma unroll
  for (int h = 0; h < HH; ++h) {
    ad[h] = ald[i * HH + h];
    float l = als[i * HH + h] + ad[h];
    l = l > 0.f ? l : 0.2f * l;
    float w = expf(l);
    den[h] = w;
    numv[h] = w * xp[((size_t)i * HH + h) * DD + d];
  }
  const int e0 = offs[t * NN + i], e1 = offs[t * NN + i + 1];
  for (int e = e0; e < e1; ++e) {
    int s = csr_src[e];
#pragma unroll
    for (int h = 0; h < HH; ++h) {
      float l = als[s * HH + h] + ad[h];
      l = l > 0.f ? l : 0.2f * l;
      float w = expf(l);
      den[h] += w;
      numv[h] += w * xp[((size_t)s * HH + h) * DD + d];
    }
  }
  float sv = 0.f;
#pragma unroll
  for (int h = 0; h < HH; ++h) sv += numv[h] / den[h];
  float val = sv * (1.f / HH) + bias[d];
  val = val > 0.f ? val : 0.01f * val;
  if (t == 0)            acc[(size_t)i * DD + d] = val;
  else if (t < TT - 1)   acc[(size_t)i * DD + d] += val;
  else                   xc[(size_t)i * DTOT + (p + 1) * DD + d] =
                             (acc[(size_t)i * DD + d] + val) * (1.f / TT);
}

__global__ void x_copy(const float* __restrict__ x, float* __restrict__ xc) {
  int i = blockIdx.x, d = threadIdx.x;
  xc[(size_t)i * DTOT + d] = x[(size_t)i * DD + d];
}

// ---------------- sort pool: per-graph top-K by last channel ----------------
__global__ __launch_bounds__(256) void sort_pool(const float* __restrict__ xc,
                                                 int* __restrict__ topk) {
  __shared__ float vals[NPG];
  __shared__ float rv[256];
  __shared__ int   ri[256];
  int b = blockIdx.x, tid = threadIdx.x;
  for (int i = tid; i < NPG; i += 256)
    vals[i] = xc[(size_t)(b * NPG + i) * DTOT + (DTOT - 1)];
  __syncthreads();
  for (int k = 0; k < KK; ++k) {
    float bv = -3.4e38f; int bi = NPG;
    for (int i = tid; i < NPG; i += 256) {
      float v = vals[i];
      if (v > bv || (v == bv && i < bi)) { bv = v; bi = i; }
    }
    rv[tid] = bv; ri[tid] = bi;
    __syncthreads();
    for (int s = 128; s > 0; s >>= 1) {
      if (tid < s) {
        float v2 = rv[tid + s]; int i2 = ri[tid + s];
        if (v2 > rv[tid] || (v2 == rv[tid] && i2 < ri[tid])) { rv[tid] = v2; ri[tid] = i2; }
      }
      __syncthreads();
    }
    if (tid == 0) { topk[b * KK + k] = b * NPG + ri[0]; vals[ri[0]] = -3.4e38f; }
    __syncthreads();
  }
}

__global__ void gather_pool(const float* __restrict__ xc, const int* __restrict__ topk,
                            const float* __restrict__ ptype, float* __restrict__ pooledT) {
  int bk = blockIdx.x;  // B*K
  int b = bk / KK, k = bk % KK;
  int node = topk[bk];
  for (int j = threadIdx.x; j < DTOT; j += 256)
    pooledT[(size_t)(k * DTOT + j) * BB + b] = xc[(size_t)node * DTOT + j];
  if (k == 0 && threadIdx.x == 0)
    pooledT[(size_t)(FIN - 1) * BB + b] = ptype[b];
}

// ---------------- FC stage 1: partial[y][j][b] = sum_{f in chunk y} inT[f][b]*W[f][j]
__global__ __launch_bounds__(256) void fc_partial(const float* __restrict__ inT,
                                                  const float* __restrict__ W,
                                                  float* __restrict__ partial,
                                                  int Kdim, int Jdim) {
  __shared__ float rows[FCCH * BB];   // 16 KiB
  const int tid = threadIdx.x;
  const int jt  = tid & 63;           // 64 j-threads
  const int bg  = tid >> 6;           // 4 b-groups
  const int j0  = blockIdx.x * 256 + jt * 4;
  const int b0  = bg * 8;
  const int f0  = blockIdx.y * FCCH;
  int nf = Kdim - f0; if (nf > FCCH) nf = FCCH;

  for (int i = tid * 4; i < nf * BB; i += 1024)
    *(float4*)&rows[i] = *(const float4*)(inT + (size_t)f0 * BB + i);
  __syncthreads();

  float acc[4][8];
#pragma unroll
  for (int a = 0; a < 4; ++a)
#pragma unroll
    for (int b = 0; b < 8; ++b) acc[a][b] = 0.f;

  const float* wp = W + (size_t)f0 * Jdim + j0;
  int ff = 0;
  for (; ff + 2 <= nf; ff += 2) {
    float4 w0 = *(const float4*)(wp + (size_t)(ff + 0) * Jdim);
    float4 w1 = *(const float4*)(wp + (size_t)(ff + 1) * Jdim);
    float4 ra0 = *(const float4*)&rows[(ff + 0) * BB + b0];
    float4 ra1 = *(const float4*)&rows[(ff + 0) * BB + b0 + 4];
    float4 rb0 = *(const float4*)&rows[(ff + 1) * BB + b0];
    float4 rb1 = *(const float4*)&rows[(ff + 1) * BB + b0 + 4];
    float wa[4] = {w0.x, w0.y, w0.z, w0.w};
    float wb[4] = {w1.x, w1.y, w1.z, w1.w};
    float r0[8] = {ra0.x, ra0.y, ra0.z, ra0.w, ra1.x, ra1.y, ra1.z, ra1.w};
    float r1[8] = {rb0.x, rb0.y, rb0.z, rb0.w, rb1.x, rb1.y, rb1.z, rb1.w};
#pragma unroll
    for (int a = 0; a < 4; ++a)
#pragma unroll
      for (int b = 0; b < 8; ++b)
        acc[a][b] += wa[a] * r0[b] + wb[a] * r1[b];
  }
  for (; ff < nf; ++ff) {
    float4 w0 = *(const float4*)(wp + (size_t)ff * Jdim);
    float4 ra0 = *(const float4*)&rows[ff * BB + b0];
    float4 ra1 = *(const float4*)&rows[ff * BB + b0 + 4];
    float wa[4] = {w0.x, w0.y, w0.z, w0.w};
    float r0[8] = {ra0.x, ra0.y, ra0.z, ra0.w, ra1.x, ra1.y, ra1.z, ra1.w};
#pragma unroll
    for (int a = 0; a < 4; ++a)
#pragma unroll
      for (int b = 0; b < 8; ++b)
        acc[a][b] += wa[a] * r0[b];
  }

#pragma unroll
  for (int a = 0; a < 4; ++a) {
    float* op = partial + ((size_t)blockIdx.y * Jdim + (j0 + a)) * BB + b0;
    *(float4*)(op)     = make_float4(acc[a][0], acc[a][1], acc[a][2], acc[a][3]);
    *(float4*)(op + 4) = make_float4(acc[a][4], acc[a][5], acc[a][6], acc[a][7]);
  }
}

// ---------------- FC stage 2: reduce partials + bias + leaky ----------------
__global__ __launch_bounds__(256) void fc_reduce(const float* __restrict__ partial,
                                                 const float* __restrict__ bias,
                                                 float* __restrict__ outT,
                                                 int Y, int Jdim) {
  int idx = blockIdx.x * 256 + threadIdx.x;   // j*BB + b
  if (idx >= Jdim * BB) return;
  size_t stride = (size_t)Jdim * BB;
  float s = 0.f;
  for (int y = 0; y < Y; ++y) s += partial[(size_t)y * stride + idx];
  float v = s + bias[idx / BB];
  outT[idx] = v > 0.f ? v : 0.01f * v;
}

__global__ __launch_bounds__(128) void fc3_kernel(const float* __restrict__ h2T,
                                                  const float* __restrict__ w3,
                                                  const float* __restrict__ b3,
                                                  float* __restrict__ out) {
  int tid = threadIdx.x;  // 128 = 32 b * 4 o
  int o = tid & 3, b = tid >> 2;
  float a0 = 0.f, a1 = 0.f, a2 = 0.f, a3 = 0.f;
  for (int f = 0; f < HID; f += 4) {
    a0 += h2T[(size_t)f * BB + b]       * w3[(size_t)f * OUTD + o];
    a1 += h2T[(size_t)(f + 1) * BB + b] * w3[(size_t)(f + 1) * OUTD + o];
    a2 += h2T[(size_t)(f + 2) * BB + b] * w3[(size_t)(f + 2) * OUTD + o];
    a3 += h2T[(size_t)(f + 3) * BB + b] * w3[(size_t)(f + 3) * OUTD + o];
  }
  out[b * OUTD + o] = a0 + a1 + a2 + a3 + b3[o];
}

extern "C" void kernel_launch(void* const* d_in, const int* in_sizes, int n_in,
                              void* d_out, int out_size, void* d_ws, size_t ws_size,
                              hipStream_t stream) {
  const float* x       = (const float*)d_in[0];
  const float* ptype   = (const float*)d_in[1];
  const float* W       = (const float*)d_in[2];
  const float* att_src = (const float*)d_in[3];
  const float* att_dst = (const float*)d_in[4];
  const float* bias_g  = (const float*)d_in[5];
  const float* fc1_w   = (const float*)d_in[6];
  const float* fc1_b   = (const float*)d_in[7];
  const float* fc2_w   = (const float*)d_in[8];
  const float* fc2_b   = (const float*)d_in[9];
  const float* fc3_w   = (const float*)d_in[10];
  const float* fc3_b   = (const float*)d_in[11];
  const int*   ei      = (const int*)d_in[12];
  const int*   ea      = (const int*)d_in[13];
  float* out = (float*)d_out;

  float* ws = (float*)d_ws;
  size_t o = 0;
  float* xc      = ws + o; o += (size_t)NN * DTOT;          // 20.97M
  float* xp      = ws + o; o += (size_t)NN * HH * DD;       // 16.78M
  float* als     = ws + o; o += (size_t)NN * HH;
  float* ald     = ws + o; o += (size_t)NN * HH;
  float* acc     = ws + o; o += (size_t)NN * DD;            // 4.19M
  float* pooledT = ws + o; o += (size_t)FIN * BB;
  float* h1      = ws + o; o += (size_t)HID * BB;
  float* h2      = ws + o; o += (size_t)HID * BB;
  float* partial = ws + o; o += (size_t)101 * HID * BB;     // 20.68M (fc1 worst case)
  int* topk    = (int*)(ws + o); o += BB * KK;
  int* deg     = (int*)(ws + o); o += TT * NN;
  int* offs    = (int*)(ws + o); o += TT * NN + 4;
  int* cursor  = (int*)(ws + o); o += TT * NN;
  int* csr_src = (int*)(ws + o); o += EE;
  // total ~64M floats = 256 MB (fill shows ws >= 1.3 GB)

  // ---- one-time per call: bucket edges by (type, dst) ----
  zero_i<<<(TT * NN + 255) / 256, 256, 0, stream>>>(deg, TT * NN);
  csr_count<<<EE / 256, 256, 0, stream>>>(ei, ea, deg);
  csr_scan<<<1, 1024, 0, stream>>>(deg, offs, cursor);
  csr_scatter<<<EE / 256, 256, 0, stream>>>(ei, ea, cursor, csr_src);

  x_copy<<<NN, 256, 0, stream>>>(x, xc);

  for (int p = 0; p < PP; ++p) {
    const float* xin = xc + (size_t)p * DD;  // column slice, row stride DTOT
    for (int t = 0; t < TT; ++t) {
      int pt = p * TT + t;
      gemm_xp<<<dim3(128, 8), 256, 0, stream>>>(xin, W + (size_t)pt * DD * HH * DD, xp);
      attn_scores<<<NN, 256, 0, stream>>>(xp, att_src + (size_t)pt * HH * DD,
                                          att_dst + (size_t)pt * HH * DD, als, ald);
      gat_aggregate<<<NN, 256, 0, stream>>>(offs, csr_src, als, ald, xp,
                                            bias_g + (size_t)pt * DD, acc, xc, t, p);
    }
  }

  sort_pool<<<BB, 256, 0, stream>>>(xc, topk);
  gather_pool<<<BB * KK, 256, 0, stream>>>(xc, topk, ptype, pooledT);

  {
    int Y1 = (FIN + FCCH - 1) / FCCH;   // 101
    fc_partial<<<dim3(HID / 256, Y1), 256, 0, stream>>>(pooledT, fc1_w, partial, FIN, HID);
    fc_reduce<<<(HID * BB + 255) / 256, 256, 0, stream>>>(partial, fc1_b, h1, Y1, HID);
    int Y2 = (HID + FCCH - 1) / FCCH;   // 50
    fc_partial<<<dim3(HID / 256, Y2), 256, 0, stream>>>(h1, fc2_w, partial, HID, HID);
    fc_reduce<<<(HID * BB + 255) / 256, 256, 0, stream>>>(partial, fc2_b, h2, Y2, HID);
  }

  fc3_kernel<<<1, 128, 0, stream>>>(h2, fc3_w, fc3_b, out);
}

// Round 4
// 2282.106 us; speedup vs baseline: 2.5497x; 1.5141x over previous
//
#include <hip/hip_runtime.h>
#include <hip/hip_fp16.h>
#include <cstdint>

#define PP 4
#define TT 4
#define NN 16384
#define DD 256
#define HH 4
#define EE 131072
#define BB 32
#define KK 10
#define OUTD 4
#define NPG 512
#define DTOT 1280   /* (P+1)*D */
#define FIN 12801
#define HID 6400
#define FCCH 128    /* f-rows per fc_partial chunk */
#define LDK 40      /* padded halves per LDS row (32 + 8) */
#define LOSCALE 2048.0f
#define INVLOSCALE (1.0f / 2048.0f)

typedef _Float16 f16x8 __attribute__((ext_vector_type(8)));
typedef float f32x4 __attribute__((ext_vector_type(4)));

// ---------------- split-f16 conversions (scaled lo: always f16-normal) ----------
// A: xc column slice [NN x 256] (row stride DTOT) -> Ahi/Alo f16 row-major [NN][256]
__global__ __launch_bounds__(256) void convert_A(const float* __restrict__ xin,
                                                 unsigned short* __restrict__ Ahi,
                                                 unsigned short* __restrict__ Alo) {
  int e4 = blockIdx.x * 256 + threadIdx.x;   // 0 .. NN*64-1
  int row = e4 >> 6, col = (e4 & 63) * 4;
  float4 v = *(const float4*)(xin + (size_t)row * DTOT + col);
  __half h0 = __float2half(v.x), h1 = __float2half(v.y),
         h2 = __float2half(v.z), h3 = __float2half(v.w);
  ushort4 hi = make_ushort4(__half_as_ushort(h0), __half_as_ushort(h1),
                            __half_as_ushort(h2), __half_as_ushort(h3));
  ushort4 lo = make_ushort4(
      __half_as_ushort(__float2half((v.x - __half2float(h0)) * LOSCALE)),
      __half_as_ushort(__float2half((v.y - __half2float(h1)) * LOSCALE)),
      __half_as_ushort(__float2half((v.z - __half2float(h2)) * LOSCALE)),
      __half_as_ushort(__float2half((v.w - __half2float(h3)) * LOSCALE)));
  *(ushort4*)&Ahi[(size_t)row * 256 + col] = hi;
  *(ushort4*)&Alo[(size_t)row * 256 + col] = lo;
}

// W: [16 pt][256 k][1024 n] fp32 -> transposed f16 hi/lo [16 pt][1024 n][256 k]
__global__ __launch_bounds__(256) void convert_W(const float* __restrict__ W,
                                                 unsigned short* __restrict__ Whi,
                                                 unsigned short* __restrict__ Wlo) {
  int pt = blockIdx.x, k4 = blockIdx.y;   // 16 x 64
  for (int rep = 0; rep < 4; ++rep) {
    int n = rep * 256 + threadIdx.x;
    unsigned short hi[4], lo[4];
#pragma unroll
    for (int i = 0; i < 4; ++i) {
      float v = W[((size_t)pt * 256 + k4 * 4 + i) * 1024 + n];
      __half h = __float2half(v);
      hi[i] = __half_as_ushort(h);
      lo[i] = __half_as_ushort(__float2half((v - __half2float(h)) * LOSCALE));
    }
    *(ushort4*)&Whi[((size_t)pt * 1024 + n) * 256 + k4 * 4] =
        make_ushort4(hi[0], hi[1], hi[2], hi[3]);
    *(ushort4*)&Wlo[((size_t)pt * 1024 + n) * 256 + k4 * 4] =
        make_ushort4(lo[0], lo[1], lo[2], lo[3]);
  }
}

// ---------------- MFMA GEMM: C = Ahi@Bhi + (Ahi@Blo + Alo@Bhi)/2^11, dual acc ------
// 128x128 tile, BK=32, 4 waves (2x2), each wave 64x64 = 4x4 fragments of 16x16x32.
__global__ __launch_bounds__(256) void gemm_split(const unsigned short* __restrict__ Ahi,
                                                  const unsigned short* __restrict__ Alo,
                                                  const unsigned short* __restrict__ Bhi,
                                                  const unsigned short* __restrict__ Blo,
                                                  float* __restrict__ C) {
  __shared__ __align__(16) unsigned short Ah[128 * LDK], Al[128 * LDK];
  __shared__ __align__(16) unsigned short Bh[128 * LDK], Bl[128 * LDK];
  const int tid = threadIdx.x;
  const int bm = blockIdx.x, bn = blockIdx.y;
  const int lane = tid & 63, w = tid >> 6;
  const int wr = w >> 1, wc = w & 1;
  const int fm = lane & 15, g = lane >> 4;
  const int srow = tid >> 1, sseg = (tid & 1) * 16;

  const unsigned short* Ag  = Ahi + (size_t)(bm * 128 + srow) * 256 + sseg;
  const unsigned short* Alg = Alo + (size_t)(bm * 128 + srow) * 256 + sseg;
  const unsigned short* Bg  = Bhi + (size_t)(bn * 128 + srow) * 256 + sseg;
  const unsigned short* Blg = Blo + (size_t)(bn * 128 + srow) * 256 + sseg;

  f32x4 acch[4][4], accl[4][4];
#pragma unroll
  for (int i = 0; i < 4; ++i)
#pragma unroll
    for (int j = 0; j < 4; ++j) {
      acch[i][j][0] = 0.f; acch[i][j][1] = 0.f; acch[i][j][2] = 0.f; acch[i][j][3] = 0.f;
      accl[i][j][0] = 0.f; accl[i][j][1] = 0.f; accl[i][j][2] = 0.f; accl[i][j][3] = 0.f;
    }

  uint4 ra = *(const uint4*)(Ag),      ra2 = *(const uint4*)(Ag + 8);
  uint4 rb = *(const uint4*)(Alg),     rb2 = *(const uint4*)(Alg + 8);
  uint4 rc = *(const uint4*)(Bg),      rc2 = *(const uint4*)(Bg + 8);
  uint4 rd = *(const uint4*)(Blg),     rd2 = *(const uint4*)(Blg + 8);

  for (int kk = 0; kk < 8; ++kk) {
    __syncthreads();
    *(uint4*)&Ah[srow * LDK + sseg] = ra;  *(uint4*)&Ah[srow * LDK + sseg + 8] = ra2;
    *(uint4*)&Al[srow * LDK + sseg] = rb;  *(uint4*)&Al[srow * LDK + sseg + 8] = rb2;
    *(uint4*)&Bh[srow * LDK + sseg] = rc;  *(uint4*)&Bh[srow * LDK + sseg + 8] = rc2;
    *(uint4*)&Bl[srow * LDK + sseg] = rd;  *(uint4*)&Bl[srow * LDK + sseg + 8] = rd2;
    __syncthreads();
    if (kk < 7) {
      int off = (kk + 1) * 32;
      ra = *(const uint4*)(Ag + off);      ra2 = *(const uint4*)(Ag + off + 8);
      rb = *(const uint4*)(Alg + off);     rb2 = *(const uint4*)(Alg + off + 8);
      rc = *(const uint4*)(Bg + off);      rc2 = *(const uint4*)(Bg + off + 8);
      rd = *(const uint4*)(Blg + off);     rd2 = *(const uint4*)(Blg + off + 8);
    }
    f16x8 fah[4], fal[4];
#pragma unroll
    for (int i = 0; i < 4; ++i) {
      fah[i] = *(const f16x8*)&Ah[(wr * 64 + i * 16 + fm) * LDK + g * 8];
      fal[i] = *(const f16x8*)&Al[(wr * 64 + i * 16 + fm) * LDK + g * 8];
    }
#pragma unroll
    for (int j = 0; j < 4; ++j) {
      f16x8 fbh = *(const f16x8*)&Bh[(wc * 64 + j * 16 + fm) * LDK + g * 8];
      f16x8 fbl = *(const f16x8*)&Bl[(wc * 64 + j * 16 + fm) * LDK + g * 8];
#pragma unroll
      for (int i = 0; i < 4; ++i) {
        acch[i][j] = __builtin_amdgcn_mfma_f32_16x16x32_f16(fah[i], fbh, acch[i][j], 0, 0, 0);
        accl[i][j] = __builtin_amdgcn_mfma_f32_16x16x32_f16(fah[i], fbl, accl[i][j], 0, 0, 0);
        accl[i][j] = __builtin_amdgcn_mfma_f32_16x16x32_f16(fal[i], fbh, accl[i][j], 0, 0, 0);
      }
    }
  }

#pragma unroll
  for (int i = 0; i < 4; ++i) {
    int row0 = bm * 128 + wr * 64 + i * 16 + g * 4;
#pragma unroll
    for (int j = 0; j < 4; ++j) {
      int col = bn * 128 + wc * 64 + j * 16 + fm;
#pragma unroll
      for (int r = 0; r < 4; ++r)
        C[(size_t)(row0 + r) * 1024 + col] = acch[i][j][r] + accl[i][j][r] * INVLOSCALE;
    }
  }
}

// ---------------- per-node attention scores ----------------
__global__ __launch_bounds__(256) void attn_scores(const float* __restrict__ xp,
                                                   const float* __restrict__ av_s,
                                                   const float* __restrict__ av_d,
                                                   float* __restrict__ als,
                                                   float* __restrict__ ald) {
  int i = blockIdx.x;
  int h = threadIdx.x >> 6;
  int lane = threadIdx.x & 63;
  const float* row = xp + ((size_t)i * HH + h) * DD;
  const float* sa = av_s + h * DD;
  const float* da = av_d + h * DD;
  float ss = 0.f, sd = 0.f;
  for (int d = lane; d < DD; d += 64) {
    float v = row[d];
    ss += v * sa[d];
    sd += v * da[d];
  }
  for (int off = 32; off > 0; off >>= 1) {
    ss += __shfl_down(ss, off, 64);
    sd += __shfl_down(sd, off, 64);
  }
  if (lane == 0) { als[i * HH + h] = ss; ald[i * HH + h] = sd; }
}

// ---------------- CSR build: bucket edges by (type, dst), excluding self-loops ----
__global__ void zero_i(int* __restrict__ p, int n) {
  int i = blockIdx.x * 256 + threadIdx.x;
  if (i < n) p[i] = 0;
}

__global__ void csr_count(const int* __restrict__ ei, const int* __restrict__ ea,
                          int* __restrict__ deg) {
  int e = blockIdx.x * 256 + threadIdx.x;
  if (e >= EE) return;
  int s = ei[e], d = ei[EE + e];
  if (s == d) return;
  atomicAdd(&deg[ea[e] * NN + d], 1);
}

__global__ __launch_bounds__(1024) void csr_scan(const int* __restrict__ deg,
                                                 int* __restrict__ offs,
                                                 int* __restrict__ cursor) {
  __shared__ int part[1024];
  const int tid = threadIdx.x;
  const int base = tid * (TT * NN / 1024);   // 64 entries per thread
  int s = 0;
  for (int i = 0; i < 64; ++i) s += deg[base + i];
  part[tid] = s;
  __syncthreads();
  for (int off = 1; off < 1024; off <<= 1) {
    int v = (tid >= off) ? part[tid - off] : 0;
    __syncthreads();
    part[tid] += v;
    __syncthreads();
  }
  int run = (tid == 0) ? 0 : part[tid - 1];
  for (int i = 0; i < 64; ++i) {
    offs[base + i] = run;
    cursor[base + i] = run;
    run += deg[base + i];
  }
  if (tid == 1023) offs[TT * NN] = run;
}

__global__ void csr_scatter(const int* __restrict__ ei, const int* __restrict__ ea,
                            int* __restrict__ cursor, int* __restrict__ csr_src) {
  int e = blockIdx.x * 256 + threadIdx.x;
  if (e >= EE) return;
  int s = ei[e], d = ei[EE + e];
  if (s == d) return;
  int pos = atomicAdd(&cursor[ea[e] * NN + d], 1);
  csr_src[pos] = s;
}

// ---------------- fused GAT aggregation (self-loop + edges + head mean) ----------
__global__ __launch_bounds__(256) void gat_aggregate(const int* __restrict__ offs,
                                                     const int* __restrict__ csr_src,
                                                     const float* __restrict__ als,
                                                     const float* __restrict__ ald,
                                                     const float* __restrict__ xp,
                                                     const float* __restrict__ bias,
                                                     float* __restrict__ acc,
                                                     float* __restrict__ xc,
                                                     int t, int p) {
  const int i = blockIdx.x, d = threadIdx.x;
  float ad[HH], den[HH], numv[HH];
#pragma unroll
  for (int h = 0; h < HH; ++h) {
    ad[h] = ald[i * HH + h];
    float l = als[i * HH + h] + ad[h];
    l = l > 0.f ? l : 0.2f * l;
    float w = expf(l);
    den[h] = w;
    numv[h] = w * xp[((size_t)i * HH + h) * DD + d];
  }
  const int e0 = offs[t * NN + i], e1 = offs[t * NN + i + 1];
  for (int e = e0; e < e1; ++e) {
    int s = csr_src[e];
#pragma unroll
    for (int h = 0; h < HH; ++h) {
      float l = als[s * HH + h] + ad[h];
      l = l > 0.f ? l : 0.2f * l;
      float w = expf(l);
      den[h] += w;
      numv[h] += w * xp[((size_t)s * HH + h) * DD + d];
    }
  }
  float sv = 0.f;
#pragma unroll
  for (int h = 0; h < HH; ++h) sv += numv[h] / den[h];
  float val = sv * (1.f / HH) + bias[d];
  val = val > 0.f ? val : 0.01f * val;
  if (t == 0)            acc[(size_t)i * DD + d] = val;
  else if (t < TT - 1)   acc[(size_t)i * DD + d] += val;
  else                   xc[(size_t)i * DTOT + (p + 1) * DD + d] =
                             (acc[(size_t)i * DD + d] + val) * (1.f / TT);
}

__global__ void x_copy(const float* __restrict__ x, float* __restrict__ xc) {
  int i = blockIdx.x, d = threadIdx.x;
  xc[(size_t)i * DTOT + d] = x[(size_t)i * DD + d];
}

// ---------------- sort pool: per-graph top-K by last channel ----------------
__global__ __launch_bounds__(256) void sort_pool(const float* __restrict__ xc,
                                                 int* __restrict__ topk) {
  __shared__ float vals[NPG];
  __shared__ float rv[256];
  __shared__ int   ri[256];
  int b = blockIdx.x, tid = threadIdx.x;
  for (int i = tid; i < NPG; i += 256)
    vals[i] = xc[(size_t)(b * NPG + i) * DTOT + (DTOT - 1)];
  __syncthreads();
  for (int k = 0; k < KK; ++k) {
    float bv = -3.4e38f; int bi = NPG;
    for (int i = tid; i < NPG; i += 256) {
      float v = vals[i];
      if (v > bv || (v == bv && i < bi)) { bv = v; bi = i; }
    }
    rv[tid] = bv; ri[tid] = bi;
    __syncthreads();
    for (int s = 128; s > 0; s >>= 1) {
      if (tid < s) {
        float v2 = rv[tid + s]; int i2 = ri[tid + s];
        if (v2 > rv[tid] || (v2 == rv[tid] && i2 < ri[tid])) { rv[tid] = v2; ri[tid] = i2; }
      }
      __syncthreads();
    }
    if (tid == 0) { topk[b * KK + k] = b * NPG + ri[0]; vals[ri[0]] = -3.4e38f; }
    __syncthreads();
  }
}

__global__ void gather_pool(const float* __restrict__ xc, const int* __restrict__ topk,
                            const float* __restrict__ ptype, float* __restrict__ pooledT) {
  int bk = blockIdx.x;  // B*K
  int b = bk / KK, k = bk % KK;
  int node = topk[bk];
  for (int j = threadIdx.x; j < DTOT; j += 256)
    pooledT[(size_t)(k * DTOT + j) * BB + b] = xc[(size_t)node * DTOT + j];
  if (k == 0 && threadIdx.x == 0)
    pooledT[(size_t)(FIN - 1) * BB + b] = ptype[b];
}

// ---------------- FC stage 1: partial[y][j][b] = sum_{f in chunk y} inT[f][b]*W[f][j]
__global__ __launch_bounds__(256) void fc_partial(const float* __restrict__ inT,
                                                  const float* __restrict__ W,
                                                  float* __restrict__ partial,
                                                  int Kdim, int Jdim) {
  __shared__ float rows[FCCH * BB];   // 16 KiB
  const int tid = threadIdx.x;
  const int jt  = tid & 63;           // 64 j-threads
  const int bg  = tid >> 6;           // 4 b-groups
  const int j0  = blockIdx.x * 256 + jt * 4;
  const int b0  = bg * 8;
  const int f0  = blockIdx.y * FCCH;
  int nf = Kdim - f0; if (nf > FCCH) nf = FCCH;

  for (int i = tid * 4; i < nf * BB; i += 1024)
    *(float4*)&rows[i] = *(const float4*)(inT + (size_t)f0 * BB + i);
  __syncthreads();

  float acc[4][8];
#pragma unroll
  for (int a = 0; a < 4; ++a)
#pragma unroll
    for (int b = 0; b < 8; ++b) acc[a][b] = 0.f;

  const float* wp = W + (size_t)f0 * Jdim + j0;
  int ff = 0;
  for (; ff + 2 <= nf; ff += 2) {
    float4 w0 = *(const float4*)(wp + (size_t)(ff + 0) * Jdim);
    float4 w1 = *(const float4*)(wp + (size_t)(ff + 1) * Jdim);
    float4 ra0 = *(const float4*)&rows[(ff + 0) * BB + b0];
    float4 ra1 = *(const float4*)&rows[(ff + 0) * BB + b0 + 4];
    float4 rb0 = *(const float4*)&rows[(ff + 1) * BB + b0];
    float4 rb1 = *(const float4*)&rows[(ff + 1) * BB + b0 + 4];
    float wa[4] = {w0.x, w0.y, w0.z, w0.w};
    float wb[4] = {w1.x, w1.y, w1.z, w1.w};
    float r0[8] = {ra0.x, ra0.y, ra0.z, ra0.w, ra1.x, ra1.y, ra1.z, ra1.w};
    float r1[8] = {rb0.x, rb0.y, rb0.z, rb0.w, rb1.x, rb1.y, rb1.z, rb1.w};
#pragma unroll
    for (int a = 0; a < 4; ++a)
#pragma unroll
      for (int b = 0; b < 8; ++b)
        acc[a][b] += wa[a] * r0[b] + wb[a] * r1[b];
  }
  for (; ff < nf; ++ff) {
    float4 w0 = *(const float4*)(wp + (size_t)ff * Jdim);
    float4 ra0 = *(const float4*)&rows[ff * BB + b0];
    float4 ra1 = *(const float4*)&rows[ff * BB + b0 + 4];
    float wa[4] = {w0.x, w0.y, w0.z, w0.w};
    float r0[8] = {ra0.x, ra0.y, ra0.z, ra0.w, ra1.x, ra1.y, ra1.z, ra1.w};
#pragma unroll
    for (int a = 0; a < 4; ++a)
#pragma unroll
      for (int b = 0; b < 8; ++b)
        acc[a][b] += wa[a] * r0[b];
  }

#pragma unroll
  for (int a = 0; a < 4; ++a) {
    float* op = partial + ((size_t)blockIdx.y * Jdim + (j0 + a)) * BB + b0;
    *(float4*)(op)     = make_float4(acc[a][0], acc[a][1], acc[a][2], acc[a][3]);
    *(float4*)(op + 4) = make_float4(acc[a][4], acc[a][5], acc[a][6], acc[a][7]);
  }
}

// ---------------- FC stage 2: reduce partials + bias + leaky ----------------
__global__ __launch_bounds__(256) void fc_reduce(const float* __restrict__ partial,
                                                 const float* __restrict__ bias,
                                                 float* __restrict__ outT,
                                                 int Y, int Jdim) {
  int idx = blockIdx.x * 256 + threadIdx.x;   // j*BB + b
  if (idx >= Jdim * BB) return;
  size_t stride = (size_t)Jdim * BB;
  float s = 0.f;
  for (int y = 0; y < Y; ++y) s += partial[(size_t)y * stride + idx];
  float v = s + bias[idx / BB];
  outT[idx] = v > 0.f ? v : 0.01f * v;
}

// ---------------- FC3: parallel partial + atomic ----------------
__global__ void fc3_init(const float* __restrict__ b3, float* __restrict__ out) {
  int i = threadIdx.x;  // 128 = BB*OUTD
  out[i] = b3[i & 3];
}

__global__ __launch_bounds__(256) void fc3_partial(const float* __restrict__ h2T,
                                                   const float* __restrict__ w3,
                                                   float* __restrict__ out) {
  int pair = threadIdx.x & 127, half = threadIdx.x >> 7;
  int b = pair >> 2, o = pair & 3;
  int f0 = blockIdx.x * 512 + half * 256;
  int f1 = f0 + 256; if (f1 > HID) f1 = HID;
  float a = 0.f;
  for (int f = f0; f < f1; ++f)
    a += h2T[(size_t)f * BB + b] * w3[(size_t)f * OUTD + o];
  if (f0 < HID) atomicAdd(&out[b * OUTD + o], a);
}

extern "C" void kernel_launch(void* const* d_in, const int* in_sizes, int n_in,
                              void* d_out, int out_size, void* d_ws, size_t ws_size,
                              hipStream_t stream) {
  const float* x       = (const float*)d_in[0];
  const float* ptype   = (const float*)d_in[1];
  const float* W       = (const float*)d_in[2];
  const float* att_src = (const float*)d_in[3];
  const float* att_dst = (const float*)d_in[4];
  const float* bias_g  = (const float*)d_in[5];
  const float* fc1_w   = (const float*)d_in[6];
  const float* fc1_b   = (const float*)d_in[7];
  const float* fc2_w   = (const float*)d_in[8];
  const float* fc2_b   = (const float*)d_in[9];
  const float* fc3_w   = (const float*)d_in[10];
  const float* fc3_b   = (const float*)d_in[11];
  const int*   ei      = (const int*)d_in[12];
  const int*   ea      = (const int*)d_in[13];
  float* out = (float*)d_out;

  float* ws = (float*)d_ws;
  size_t o = 0;
  float* xc      = ws + o; o += (size_t)NN * DTOT;          // 20.97M
  float* xp      = ws + o; o += (size_t)NN * HH * DD;       // 16.78M
  float* als     = ws + o; o += (size_t)NN * HH;
  float* ald     = ws + o; o += (size_t)NN * HH;
  float* acc     = ws + o; o += (size_t)NN * DD;            // 4.19M
  float* pooledT = ws + o; o += (size_t)FIN * BB;
  float* h1      = ws + o; o += (size_t)HID * BB;
  float* h2      = ws + o; o += (size_t)HID * BB;
  float* partial = ws + o; o += (size_t)101 * HID * BB;     // 20.68M (fc1 worst case)
  unsigned short* Ahi = (unsigned short*)(ws + o); o += (size_t)NN * 256 / 2;
  unsigned short* Alo = (unsigned short*)(ws + o); o += (size_t)NN * 256 / 2;
  unsigned short* Whi = (unsigned short*)(ws + o); o += (size_t)16 * 1024 * 256 / 2;
  unsigned short* Wlo = (unsigned short*)(ws + o); o += (size_t)16 * 1024 * 256 / 2;
  int* topk    = (int*)(ws + o); o += BB * KK;
  int* deg     = (int*)(ws + o); o += TT * NN;
  int* offs    = (int*)(ws + o); o += TT * NN + 4;
  int* cursor  = (int*)(ws + o); o += TT * NN;
  int* csr_src = (int*)(ws + o); o += EE;
  // total ~72M floats = 288 MB (ws >= 1.28 GB per fill counters)

  // ---- one-time: weight split-f16 + transpose; edge CSR by (type, dst) ----
  convert_W<<<dim3(16, 64), 256, 0, stream>>>(W, Whi, Wlo);
  zero_i<<<(TT * NN + 255) / 256, 256, 0, stream>>>(deg, TT * NN);
  csr_count<<<EE / 256, 256, 0, stream>>>(ei, ea, deg);
  csr_scan<<<1, 1024, 0, stream>>>(deg, offs, cursor);
  csr_scatter<<<EE / 256, 256, 0, stream>>>(ei, ea, cursor, csr_src);

  x_copy<<<NN, 256, 0, stream>>>(x, xc);

  for (int p = 0; p < PP; ++p) {
    const float* xin = xc + (size_t)p * DD;  // column slice, row stride DTOT
    convert_A<<<NN / 4, 256, 0, stream>>>(xin, Ahi, Alo);
    for (int t = 0; t < TT; ++t) {
      int pt = p * TT + t;
      gemm_split<<<dim3(128, 8), 256, 0, stream>>>(
          Ahi, Alo, Whi + (size_t)pt * 1024 * 256, Wlo + (size_t)pt * 1024 * 256, xp);
      attn_scores<<<NN, 256, 0, stream>>>(xp, att_src + (size_t)pt * HH * DD,
                                          att_dst + (size_t)pt * HH * DD, als, ald);
      gat_aggregate<<<NN, 256, 0, stream>>>(offs, csr_src, als, ald, xp,
                                            bias_g + (size_t)pt * DD, acc, xc, t, p);
    }
  }

  sort_pool<<<BB, 256, 0, stream>>>(xc, topk);
  gather_pool<<<BB * KK, 256, 0, stream>>>(xc, topk, ptype, pooledT);

  {
    int Y1 = (FIN + FCCH - 1) / FCCH;   // 101
    fc_partial<<<dim3(HID / 256, Y1), 256, 0, stream>>>(pooledT, fc1_w, partial, FIN, HID);
    fc_reduce<<<(HID * BB + 255) / 256, 256, 0, stream>>>(partial, fc1_b, h1, Y1, HID);
    int Y2 = (HID + FCCH - 1) / FCCH;   // 50
    fc_partial<<<dim3(HID / 256, Y2), 256, 0, stream>>>(h1, fc2_w, partial, HID, HID);
    fc_reduce<<<(HID * BB + 255) / 256, 256, 0, stream>>>(partial, fc2_b, h2, Y2, HID);
  }

  fc3_init<<<1, BB * OUTD, 0, stream>>>(fc3_b, out);
  fc3_partial<<<(HID + 511) / 512, 256, 0, stream>>>(h2, fc3_w, out);
}